// Round 3
// baseline (482.272 us; speedup 1.0000x reference)
//
#include <hip/hip_runtime.h>
#include <float.h>

#define NNODES 30000
#define NEDGES 480000
#define NFEATK 128
#define NH 16
#define NC 32
#define HC 512            // NH*NC
#define NCLASSES 10
#define NG 64
#define CAP 96            // padded per-node edge capacity (max deg ~45 for Poisson(16))
#define NSLICE 8          // 8 slices x 2 heads; slice pinned to XCD via bid%8

using half2v = __attribute__((ext_vector_type(2))) _Float16;
using half4 = __attribute__((ext_vector_type(4))) _Float16;
using half8 = __attribute__((ext_vector_type(8))) _Float16;
using f32x4 = __attribute__((ext_vector_type(4))) float;

// ---------------- merged prep: conversions + bucket init ----------------
__global__ void prep0_kernel(const float* __restrict__ x, _Float16* __restrict__ xh,
                             const float* __restrict__ Wl1, const float* __restrict__ Wr1,
                             _Float16* __restrict__ Wlt1, _Float16* __restrict__ Wrt1,
                             const float* __restrict__ Wl2, const float* __restrict__ Wr2,
                             _Float16* __restrict__ Wlt2, _Float16* __restrict__ Wrt2,
                             int* __restrict__ cnt, int* __restrict__ csr) {
    int gtid = blockIdx.x * blockDim.x + threadIdx.x;
    int gstride = gridDim.x * blockDim.x;
    // x -> fp16 (float4-granular)
    for (int i = gtid; i < NNODES * NFEATK / 4; i += gstride) {
        float4 v = *(const float4*)&x[i * 4];
        half4 h = {(_Float16)v.x, (_Float16)v.y, (_Float16)v.z, (_Float16)v.w};
        *(half4*)&xh[i * 4] = h;
    }
    // W1 transposes (both l and r)
    for (int i = gtid; i < 2 * 512 * NFEATK; i += gstride) {
        int sel = i >= 512 * NFEATK;
        int idx = i - sel * 512 * NFEATK;
        const float* W = sel ? Wr1 : Wl1;
        _Float16* Wt = sel ? Wrt1 : Wlt1;
        int n = idx & 511, k = idx >> 9;
        Wt[n * NFEATK + k] = (_Float16)W[idx];
    }
    // W2 transposes
    for (int i = gtid; i < 2 * 512 * NC; i += gstride) {
        int sel = i >= 512 * NC;
        int idx = i - sel * 512 * NC;
        const float* W = sel ? Wr2 : Wl2;
        _Float16* Wt = sel ? Wrt2 : Wlt2;
        int n = idx & 511, k = idx >> 9;
        Wt[n * NC + k] = (_Float16)W[idx];
    }
    // bucket init: self-loop in slot 0, cnt = 1
    for (int i = gtid; i < NNODES; i += gstride) {
        cnt[i] = 1;
        csr[i * CAP] = i;
    }
}

// ---------------- bucket scatter: one atomic pass, no count/scan ----------------
__global__ void scatter_kernel(const int* __restrict__ src, const int* __restrict__ dst,
                               int* __restrict__ cnt, int* __restrict__ csr) {
    int e = blockIdx.x * blockDim.x + threadIdx.x;
    if (e >= NEDGES) return;
    int s = src[e], d = dst[e];
    int pos = atomicAdd(&cnt[d], 1);
    csr[d * CAP + pos] = s;
}

// ---------------- dual MFMA GEMM (unchanged) ----------------
template <int K>
__launch_bounds__(256)
__global__ void dual_gemm_kernel(const _Float16* __restrict__ A,
                                 const _Float16* __restrict__ Wlt, const _Float16* __restrict__ Wrt,
                                 const float* __restrict__ bl, const float* __restrict__ br,
                                 _Float16* __restrict__ Yl, _Float16* __restrict__ Yr) {
    constexpr int Kc = K / 8;
    constexpr int AH = 64 * K;
    constexpr int BH = 128 * K;
    constexpr int YSH = 64 * 136;
    constexpr int SMEMH = (AH + BH > YSH) ? (AH + BH) : YSH;
    __shared__ __align__(16) _Float16 smem[SMEMH];
    _Float16* as = smem;
    _Float16* bs = smem + AH;

    int tid = threadIdx.x;
    int sel = blockIdx.y >> 2;
    int nbase = (blockIdx.y & 3) * 128;
    const _Float16* Bt = sel ? Wrt : Wlt;
    const float* bias = sel ? br : bl;
    _Float16* Y = sel ? Yr : Yl;
    int mb = blockIdx.x;

    for (int c = tid; c < 64 * Kc; c += 256) {
        int row = c / Kc, k8 = c % Kc;
        int arow = mb * 64 + row; if (arow > NNODES - 1) arow = NNODES - 1;
        half8 v = *(const half8*)&A[(size_t)arow * K + k8 * 8];
        *(half8*)&as[(row * Kc + (k8 ^ (row & (Kc - 1)))) * 8] = v;
    }
    for (int c = tid; c < 128 * Kc; c += 256) {
        int row = c / Kc, k8 = c % Kc;
        half8 v = *(const half8*)&Bt[(size_t)(nbase + row) * K + k8 * 8];
        *(half8*)&bs[(row * Kc + (k8 ^ (row & (Kc - 1)))) * 8] = v;
    }
    __syncthreads();

    int wave = tid >> 6, lane = tid & 63;
    int quad = lane >> 4, l16 = lane & 15;
    int am = l16 & (Kc - 1);

    f32x4 acc[8];
    #pragma unroll
    for (int f = 0; f < 8; f++) acc[f] = (f32x4){0.f, 0.f, 0.f, 0.f};

    #pragma unroll
    for (int kk = 0; kk < Kc; kk += 4) {
        int k8 = (kk + quad) ^ am;
        half8 a = *(const half8*)&as[((wave * 16 + l16) * Kc + k8) * 8];
        #pragma unroll
        for (int f = 0; f < 8; f++) {
            half8 b = *(const half8*)&bs[((f * 16 + l16) * Kc + k8) * 8];
            acc[f] = __builtin_amdgcn_mfma_f32_16x16x32_f16(a, b, acc[f], 0, 0, 0);
        }
    }
    __syncthreads();

    _Float16* ys = smem;
    #pragma unroll
    for (int f = 0; f < 8; f++) {
        float bv = bias[nbase + f * 16 + l16];
        #pragma unroll
        for (int r = 0; r < 4; r++) {
            ys[(wave * 16 + quad * 4 + r) * 136 + f * 16 + l16] = (_Float16)(acc[f][r] + bv);
        }
    }
    __syncthreads();
    int mtop = mb * 64;
    for (int c = tid; c < 64 * 16; c += 256) {
        int r = c >> 4, cc = (c & 15) * 8;
        int grow = mtop + r;
        if (grow < NNODES)
            *(half8*)&Y[(size_t)grow * HC + nbase + cc] = *(half8*)&ys[r * 136 + cc];
    }
}

// ---------------- fused GATv2 edge stage: XCD-pinned 2-head slices ----------------
// grid = (NNODES/4) * 8 blocks of 256 threads.
// slice = blockIdx.x & 7  -> lands on XCD (bid % 8): each XCD's L2 caches only
// its slice's 128B row-chunks of xlh (30000*128B = 3.75MB < 4MiB L2).
// Wave = 1 node; lane = (edge_slot = t>>3) x (8 channels at (t&7)*8).
__device__ inline half2v lrelu2(half2v e) {
    half2v s = e * half2v{(_Float16)0.2f, (_Float16)0.2f};
    return __builtin_elementwise_max(e, s);
}

#if __has_builtin(__builtin_amdgcn_fdot2)
#define FDOT2(a, b, c) __builtin_amdgcn_fdot2((a), (b), (c), false)
#else
__device__ inline float fdot2_sw(half2v a, half2v b, float c) {
    half2v p = a * b;
    return c + (float)p.x + (float)p.y;
}
#define FDOT2(a, b, c) fdot2_sw((a), (b), (c))
#endif

__launch_bounds__(256)
__global__ void gat_edge_kernel(const _Float16* __restrict__ xlh, const _Float16* __restrict__ xrh,
                                const float* __restrict__ att,
                                const int* __restrict__ cnt, const int* __restrict__ csr_src,
                                float* __restrict__ part) {   // [NSLICE][NNODES][NC]
    int b = blockIdx.x;
    int slice = b & 7;                   // XCD-pinned slice (2 heads, 64 ch)
    int wv = threadIdx.x >> 6;
    int t = threadIdx.x & 63;
    int d = (b >> 3) * 4 + wv;           // node
    int slot = t >> 3;                   // 8 edge slots
    int c8 = (t & 7) * 8;                // channel-in-slice base
    int colbase = slice * 64;

    // xr (query side): streamed once per pass -> nontemporal
    half8 xrq = __builtin_nontemporal_load(
        (const half8*)&xrh[(size_t)d * HC + colbase + c8]);
    half2v xr0 = {xrq[0], xrq[1]}, xr1 = {xrq[2], xrq[3]};
    half2v xr2 = {xrq[4], xrq[5]}, xr3 = {xrq[6], xrq[7]};
    float4 atta = *(const float4*)&att[colbase + c8];
    float4 attb = *(const float4*)&att[colbase + c8 + 4];
    half2v at0 = {(_Float16)atta.x, (_Float16)atta.y};
    half2v at1 = {(_Float16)atta.z, (_Float16)atta.w};
    half2v at2 = {(_Float16)attb.x, (_Float16)attb.y};
    half2v at3 = {(_Float16)attb.z, (_Float16)attb.w};

    int deg = __builtin_nontemporal_load(&cnt[d]);
    int beg = d * CAP;

    float l = 0.f;
    float a[8];
    #pragma unroll
    for (int c = 0; c < 8; c++) a[c] = 0.f;

    for (int it = 0; it < deg; it += 8) {
        int e = it + slot;
        int valid = e < deg;
        int s = __builtin_nontemporal_load(&csr_src[beg + (valid ? e : 0)]);
        // the hot gather: stays cached in this XCD's L2 (regular load)
        half8 q = *(const half8*)&xlh[(size_t)s * HC + colbase + c8];

        float v = 0.f;
        v = FDOT2(lrelu2(half2v{q[0], q[1]} + xr0), at0, v);
        v = FDOT2(lrelu2(half2v{q[2], q[3]} + xr1), at1, v);
        v = FDOT2(lrelu2(half2v{q[4], q[5]} + xr2), at2, v);
        v = FDOT2(lrelu2(half2v{q[6], q[7]} + xr3), at3, v);

        // head reduce: 4 lanes per head within the 8-lane slot group
        v += __shfl_xor(v, 1);
        v += __shfl_xor(v, 2);

        float p = valid ? __expf(v) : 0.f;
        l += p;
        #pragma unroll
        for (int c = 0; c < 8; c++) a[c] += p * (float)q[c];
    }

    // sum over the 8 edge slots (same (t&7) lanes)
    #pragma unroll
    for (int off = 8; off < 64; off <<= 1) {
        l += __shfl_xor(l, off);
        #pragma unroll
        for (int c = 0; c < 8; c++) a[c] += __shfl_xor(a[c], off);
    }
    // per-head normalize (l uniform within each 4-lane head half)
    float inv = 1.0f / l;
    #pragma unroll
    for (int c = 0; c < 8; c++) a[c] *= inv;
    // cross-head partial sum: lane k (head A, ch-in-head k*8) + lane k^4 (head B, same ch-in-head)
    #pragma unroll
    for (int c = 0; c < 8; c++) a[c] += __shfl_xor(a[c], 4);

    if (t < 4) {
        f32x4 o0 = {a[0], a[1], a[2], a[3]};
        f32x4 o1 = {a[4], a[5], a[6], a[7]};
        size_t o = ((size_t)slice * NNODES + d) * NC + t * 8;
        __builtin_nontemporal_store(o0, (f32x4*)&part[o]);
        __builtin_nontemporal_store(o1, (f32x4*)&part[o + 4]);
    }
}

// ---------------- slice-partial reduce: sum 8 slices, /NH, +bias, leaky ----------------
template <typename OUT>
__launch_bounds__(256)
__global__ void head_reduce_kernel(const float* __restrict__ part, const float* __restrict__ bvec,
                                   OUT* __restrict__ hout) {
    int i = blockIdx.x * blockDim.x + threadIdx.x;   // NNODES*8 float4-units
    if (i >= NNODES * (NC / 4)) return;
    int d = i >> 3, c4 = (i & 7) * 4;
    f32x4 s = {0.f, 0.f, 0.f, 0.f};
    #pragma unroll
    for (int sl = 0; sl < NSLICE; sl++) {
        f32x4 v = *(const f32x4*)&part[((size_t)sl * NNODES + d) * NC + c4];
        s += v;
    }
    const f32x4 bv = *(const f32x4*)&bvec[c4];
    #pragma unroll
    for (int j = 0; j < 4; j++) {
        float r = s[j] * (1.0f / (float)NH) + bv[j];
        r = (r > 0.f) ? r : 0.01f * r;
        hout[(size_t)d * NC + c4 + j] = (OUT)r;
    }
}

// ---------------- fused pool + classifier (unchanged) ----------------
__launch_bounds__(1024)
__global__ void pool_classify_kernel(const float* __restrict__ h, const int* __restrict__ batch,
                                     const float* __restrict__ Wc, const float* __restrict__ bc,
                                     float* __restrict__ out) {
    int g = blockIdx.x;
    int lo = 0, hi = NNODES;
    while (lo < hi) { int mid = (lo + hi) >> 1; if (batch[mid] < g) lo = mid + 1; else hi = mid; }
    int start = lo;
    hi = NNODES;
    while (lo < hi) { int mid = (lo + hi) >> 1; if (batch[mid] <= g) lo = mid + 1; else hi = mid; }
    int endn = lo;
    int cntg = endn - start;

    int tid = threadIdx.x;
    int c = tid & 31, nl = tid >> 5;              // 32 node-lanes x 32 channels
    float s = 0.f;
    for (int n = start + nl; n < endn; n += 32) s += h[n * NC + c];
    __shared__ float red[1024];
    red[tid] = s;
    __syncthreads();
    if (tid < 32) {
        float t = 0.f;
        #pragma unroll
        for (int j = 0; j < 32; j++) t += red[j * 32 + tid];
        red[tid] = t / fmaxf((float)cntg, 1.0f);
    }
    __syncthreads();
    if (tid < NCLASSES) {
        float sum = bc[tid];
        #pragma unroll
        for (int cc = 0; cc < NC; cc++) sum += red[cc] * Wc[cc * NCLASSES + tid];
        out[g * NCLASSES + tid] = sum;
    }
}

// ---------------- launch ----------------

extern "C" void kernel_launch(void* const* d_in, const int* in_sizes, int n_in,
                              void* d_out, int out_size, void* d_ws, size_t ws_size,
                              hipStream_t stream) {
    const float* x    = (const float*)d_in[0];
    const float* Wl1  = (const float*)d_in[1];
    const float* bl1  = (const float*)d_in[2];
    const float* Wr1  = (const float*)d_in[3];
    const float* br1  = (const float*)d_in[4];
    const float* att1 = (const float*)d_in[5];
    const float* b1   = (const float*)d_in[6];
    const float* Wl2  = (const float*)d_in[7];
    const float* bl2  = (const float*)d_in[8];
    const float* Wr2  = (const float*)d_in[9];
    const float* br2  = (const float*)d_in[10];
    const float* att2 = (const float*)d_in[11];
    const float* b2   = (const float*)d_in[12];
    const float* Wc   = (const float*)d_in[13];
    const float* bc   = (const float*)d_in[14];
    const int* ei     = (const int*)d_in[15];
    const int* batch  = (const int*)d_in[16];
    float* out = (float*)d_out;

    const int* srcp = ei;
    const int* dstp = ei + NEDGES;

    char* ws = (char*)d_ws;
    size_t off = 0;
    auto alloc = [&](size_t bytes) -> void* {
        void* p = ws + off;
        off += (bytes + 255) & ~(size_t)255;
        return p;
    };
    _Float16* xlh  = (_Float16*)alloc(sizeof(_Float16) * (size_t)NNODES * HC);
    _Float16* xrh  = (_Float16*)alloc(sizeof(_Float16) * (size_t)NNODES * HC);
    _Float16* xh   = (_Float16*)alloc(sizeof(_Float16) * (size_t)NNODES * NFEATK);
    _Float16* h1   = (_Float16*)alloc(sizeof(_Float16) * (size_t)NNODES * NC);
    float* h2      = (float*)alloc(sizeof(float) * (size_t)NNODES * NC);
    float* part    = (float*)alloc(sizeof(float) * (size_t)NSLICE * NNODES * NC);
    _Float16* Wlt1 = (_Float16*)alloc(sizeof(_Float16) * 512 * NFEATK);
    _Float16* Wrt1 = (_Float16*)alloc(sizeof(_Float16) * 512 * NFEATK);
    _Float16* Wlt2 = (_Float16*)alloc(sizeof(_Float16) * 512 * NC);
    _Float16* Wrt2 = (_Float16*)alloc(sizeof(_Float16) * 512 * NC);
    int*   cnt     = (int*)alloc(sizeof(int) * NNODES);
    int*   csr     = (int*)alloc(sizeof(int) * (size_t)NNODES * CAP);

    // prep: conversions + bucket init (one dispatch)
    prep0_kernel<<<512, 256, 0, stream>>>(x, xh, Wl1, Wr1, Wlt1, Wrt1,
                                          Wl2, Wr2, Wlt2, Wrt2, cnt, csr);
    // bucket scatter (one atomic pass; no count/scan)
    scatter_kernel<<<(NEDGES + 255) / 256, 256, 0, stream>>>(srcp, dstp, cnt, csr);

    const int MB = (NNODES + 63) / 64;     // 469
    const int EB = (NNODES / 4) * NSLICE;  // 60000 edge-stage blocks
    const int RB = (NNODES * (NC / 4) + 255) / 256;

    // Layer 1
    dual_gemm_kernel<NFEATK><<<dim3(MB, 8), 256, 0, stream>>>(xh, Wlt1, Wrt1, bl1, br1, xlh, xrh);
    gat_edge_kernel<<<EB, 256, 0, stream>>>(xlh, xrh, att1, cnt, csr, part);
    head_reduce_kernel<_Float16><<<RB, 256, 0, stream>>>(part, b1, h1);

    // Layer 2
    dual_gemm_kernel<NC><<<dim3(MB, 8), 256, 0, stream>>>(h1, Wlt2, Wrt2, bl2, br2, xlh, xrh);
    gat_edge_kernel<<<EB, 256, 0, stream>>>(xlh, xrh, att2, cnt, csr, part);
    head_reduce_kernel<float><<<RB, 256, 0, stream>>>(part, b2, h2);

    // Pool + classify
    pool_classify_kernel<<<NG, 1024, 0, stream>>>(h2, batch, Wc, bc, out);
}

// Round 4
// 367.537 us; speedup vs baseline: 1.3122x; 1.3122x over previous
//
#include <hip/hip_runtime.h>
#include <float.h>

#define NNODES 30000
#define NEDGES 480000
#define NFEATK 128
#define NH 16
#define NC 32
#define HC 512            // NH*NC
#define NCLASSES 10
#define NG 64
#define CAP 96            // padded per-node edge capacity (max deg ~45 for Poisson(16))
#define NSLICE 8          // 8 slices x 2 heads; slice pinned to XCD via bid%8

using half2v = __attribute__((ext_vector_type(2))) _Float16;
using half4 = __attribute__((ext_vector_type(4))) _Float16;
using half8 = __attribute__((ext_vector_type(8))) _Float16;
using f32x4 = __attribute__((ext_vector_type(4))) float;

// ---------------- merged prep: conversions + bucket init ----------------
__global__ void prep0_kernel(const float* __restrict__ x, _Float16* __restrict__ xh,
                             const float* __restrict__ Wl1, const float* __restrict__ Wr1,
                             _Float16* __restrict__ Wlt1, _Float16* __restrict__ Wrt1,
                             const float* __restrict__ Wl2, const float* __restrict__ Wr2,
                             _Float16* __restrict__ Wlt2, _Float16* __restrict__ Wrt2,
                             int* __restrict__ cnt, unsigned short* __restrict__ csr) {
    int gtid = blockIdx.x * blockDim.x + threadIdx.x;
    int gstride = gridDim.x * blockDim.x;
    // x -> fp16 (float4-granular)
    for (int i = gtid; i < NNODES * NFEATK / 4; i += gstride) {
        float4 v = *(const float4*)&x[i * 4];
        half4 h = {(_Float16)v.x, (_Float16)v.y, (_Float16)v.z, (_Float16)v.w};
        *(half4*)&xh[i * 4] = h;
    }
    // W1 transposes (both l and r)
    for (int i = gtid; i < 2 * 512 * NFEATK; i += gstride) {
        int sel = i >= 512 * NFEATK;
        int idx = i - sel * 512 * NFEATK;
        const float* W = sel ? Wr1 : Wl1;
        _Float16* Wt = sel ? Wrt1 : Wlt1;
        int n = idx & 511, k = idx >> 9;
        Wt[n * NFEATK + k] = (_Float16)W[idx];
    }
    // W2 transposes
    for (int i = gtid; i < 2 * 512 * NC; i += gstride) {
        int sel = i >= 512 * NC;
        int idx = i - sel * 512 * NC;
        const float* W = sel ? Wr2 : Wl2;
        _Float16* Wt = sel ? Wrt2 : Wlt2;
        int n = idx & 511, k = idx >> 9;
        Wt[n * NC + k] = (_Float16)W[idx];
    }
    // bucket init: self-loop in slot 0, cnt = 1
    for (int i = gtid; i < NNODES; i += gstride) {
        cnt[i] = 1;
        csr[i * CAP] = (unsigned short)i;
    }
}

// ---------------- bucket scatter: one atomic pass, u16 payload ----------------
__global__ void scatter_kernel(const int* __restrict__ src, const int* __restrict__ dst,
                               int* __restrict__ cnt, unsigned short* __restrict__ csr) {
    int e = blockIdx.x * blockDim.x + threadIdx.x;
    if (e >= NEDGES) return;
    int s = src[e], d = dst[e];
    int pos = atomicAdd(&cnt[d], 1);
    csr[d * CAP + pos] = (unsigned short)s;
}

// ---------------- dual MFMA GEMM (unchanged) ----------------
template <int K>
__launch_bounds__(256)
__global__ void dual_gemm_kernel(const _Float16* __restrict__ A,
                                 const _Float16* __restrict__ Wlt, const _Float16* __restrict__ Wrt,
                                 const float* __restrict__ bl, const float* __restrict__ br,
                                 _Float16* __restrict__ Yl, _Float16* __restrict__ Yr) {
    constexpr int Kc = K / 8;
    constexpr int AH = 64 * K;
    constexpr int BH = 128 * K;
    constexpr int YSH = 64 * 136;
    constexpr int SMEMH = (AH + BH > YSH) ? (AH + BH) : YSH;
    __shared__ __align__(16) _Float16 smem[SMEMH];
    _Float16* as = smem;
    _Float16* bs = smem + AH;

    int tid = threadIdx.x;
    int sel = blockIdx.y >> 2;
    int nbase = (blockIdx.y & 3) * 128;
    const _Float16* Bt = sel ? Wrt : Wlt;
    const float* bias = sel ? br : bl;
    _Float16* Y = sel ? Yr : Yl;
    int mb = blockIdx.x;

    for (int c = tid; c < 64 * Kc; c += 256) {
        int row = c / Kc, k8 = c % Kc;
        int arow = mb * 64 + row; if (arow > NNODES - 1) arow = NNODES - 1;
        half8 v = *(const half8*)&A[(size_t)arow * K + k8 * 8];
        *(half8*)&as[(row * Kc + (k8 ^ (row & (Kc - 1)))) * 8] = v;
    }
    for (int c = tid; c < 128 * Kc; c += 256) {
        int row = c / Kc, k8 = c % Kc;
        half8 v = *(const half8*)&Bt[(size_t)(nbase + row) * K + k8 * 8];
        *(half8*)&bs[(row * Kc + (k8 ^ (row & (Kc - 1)))) * 8] = v;
    }
    __syncthreads();

    int wave = tid >> 6, lane = tid & 63;
    int quad = lane >> 4, l16 = lane & 15;
    int am = l16 & (Kc - 1);

    f32x4 acc[8];
    #pragma unroll
    for (int f = 0; f < 8; f++) acc[f] = (f32x4){0.f, 0.f, 0.f, 0.f};

    #pragma unroll
    for (int kk = 0; kk < Kc; kk += 4) {
        int k8 = (kk + quad) ^ am;
        half8 a = *(const half8*)&as[((wave * 16 + l16) * Kc + k8) * 8];
        #pragma unroll
        for (int f = 0; f < 8; f++) {
            half8 b = *(const half8*)&bs[((f * 16 + l16) * Kc + k8) * 8];
            acc[f] = __builtin_amdgcn_mfma_f32_16x16x32_f16(a, b, acc[f], 0, 0, 0);
        }
    }
    __syncthreads();

    _Float16* ys = smem;
    #pragma unroll
    for (int f = 0; f < 8; f++) {
        float bv = bias[nbase + f * 16 + l16];
        #pragma unroll
        for (int r = 0; r < 4; r++) {
            ys[(wave * 16 + quad * 4 + r) * 136 + f * 16 + l16] = (_Float16)(acc[f][r] + bv);
        }
    }
    __syncthreads();
    int mtop = mb * 64;
    for (int c = tid; c < 64 * 16; c += 256) {
        int r = c >> 4, cc = (c & 15) * 8;
        int grow = mtop + r;
        if (grow < NNODES)
            *(half8*)&Y[(size_t)grow * HC + nbase + cc] = *(half8*)&ys[r * 136 + cc];
    }
}

// ---------------- fused GATv2 edge stage: XCD-pinned slices, 2 nodes/wave ----------------
// grid = (NNODES/8) * 8 blocks of 256 threads (4 waves x 2 nodes).
// slice = blockIdx.x & 7 -> XCD (bid % 8): per-XCD hot set = 30000 x 128B = 3.75MB < 4MiB L2.
// Lane map: node = t>>5 (2 nodes), slot = (t>>3)&3 (4 edge slots), ch8 = (t&7)*8.
__device__ inline half2v lrelu2(half2v e) {
    half2v s = e * half2v{(_Float16)0.2f, (_Float16)0.2f};
    return __builtin_elementwise_max(e, s);
}

#if __has_builtin(__builtin_amdgcn_fdot2)
#define FDOT2(a, b, c) __builtin_amdgcn_fdot2((a), (b), (c), false)
#else
__device__ inline float fdot2_sw(half2v a, half2v b, float c) {
    half2v p = a * b;
    return c + (float)p.x + (float)p.y;
}
#define FDOT2(a, b, c) fdot2_sw((a), (b), (c))
#endif

__launch_bounds__(256)
__global__ void gat_edge_kernel(const _Float16* __restrict__ xlh, const _Float16* __restrict__ xrh,
                                const float* __restrict__ att,
                                const int* __restrict__ cnt, const unsigned short* __restrict__ csr_src,
                                float* __restrict__ part) {   // [NSLICE][NNODES][NC]
    int b = blockIdx.x;
    int slice = b & 7;                   // XCD-pinned slice (2 heads, 64 ch)
    int wv = threadIdx.x >> 6;
    int t = threadIdx.x & 63;
    int d0 = (b >> 3) * 8 + wv * 2;      // first node of this wave
    int nh = t >> 5;                     // node half (0/1)
    int d = d0 + nh;
    int slot = (t >> 3) & 3;             // 4 edge slots per node
    int ch8 = (t & 7) * 8;               // channel-in-slice base
    int colbase = slice * 64;

    // xr (query side): streamed once per pass -> nontemporal
    half8 xrq = __builtin_nontemporal_load(
        (const half8*)&xrh[(size_t)d * HC + colbase + ch8]);
    half2v xr0 = {xrq[0], xrq[1]}, xr1 = {xrq[2], xrq[3]};
    half2v xr2 = {xrq[4], xrq[5]}, xr3 = {xrq[6], xrq[7]};
    float4 atta = *(const float4*)&att[colbase + ch8];
    float4 attb = *(const float4*)&att[colbase + ch8 + 4];
    half2v at0 = {(_Float16)atta.x, (_Float16)atta.y};
    half2v at1 = {(_Float16)atta.z, (_Float16)atta.w};
    half2v at2 = {(_Float16)attb.x, (_Float16)attb.y};
    half2v at3 = {(_Float16)attb.z, (_Float16)attb.w};

    int dg0 = cnt[d0], dg1 = cnt[d0 + 1];
    int mydeg = nh ? dg1 : dg0;
    int dmax = dg0 > dg1 ? dg0 : dg1;
    size_t beg = (size_t)d * CAP;

    float l = 0.f;
    float a[8];
    #pragma unroll
    for (int c = 0; c < 8; c++) a[c] = 0.f;

    for (int it = 0; it < dmax; it += 4) {
        int e = it + slot;
        int valid = e < mydeg;
        int s = csr_src[beg + (valid ? e : 0)];
        // the hot gather: stays cached in this XCD's L2
        half8 q = *(const half8*)&xlh[(size_t)s * HC + colbase + ch8];

        float v = 0.f;
        v = FDOT2(lrelu2(half2v{q[0], q[1]} + xr0), at0, v);
        v = FDOT2(lrelu2(half2v{q[2], q[3]} + xr1), at1, v);
        v = FDOT2(lrelu2(half2v{q[4], q[5]} + xr2), at2, v);
        v = FDOT2(lrelu2(half2v{q[6], q[7]} + xr3), at3, v);

        // head reduce: 4 lanes per head (head = (t>>2)&1 within 8-lane edge group)
        v += __shfl_xor(v, 1);
        v += __shfl_xor(v, 2);

        float p = valid ? __expf(v) : 0.f;
        l += p;
        #pragma unroll
        for (int c = 0; c < 8; c++) a[c] += p * (float)q[c];
    }

    // slot reduce (4 slots within each 32-lane node half): 2 levels
    #pragma unroll
    for (int off = 8; off < 32; off <<= 1) {
        l += __shfl_xor(l, off);
        #pragma unroll
        for (int c = 0; c < 8; c++) a[c] += __shfl_xor(a[c], off);
    }
    // per-head normalize (l uniform within each 4-lane head group)
    float inv = 1.0f / l;
    #pragma unroll
    for (int c = 0; c < 8; c++) a[c] *= inv;
    // cross-head partial sum: lane k (head A, ch-in-head k*8) + lane k^4 (head B)
    #pragma unroll
    for (int c = 0; c < 8; c++) a[c] += __shfl_xor(a[c], 4);

    if ((t & 31) < 4) {
        f32x4 o0 = {a[0], a[1], a[2], a[3]};
        f32x4 o1 = {a[4], a[5], a[6], a[7]};
        size_t o = ((size_t)slice * NNODES + d) * NC + (t & 3) * 8;
        __builtin_nontemporal_store(o0, (f32x4*)&part[o]);
        __builtin_nontemporal_store(o1, (f32x4*)&part[o + 4]);
    }
}

// ---------------- slice-partial reduce: sum 8 slices, /NH, +bias, leaky ----------------
template <typename OUT>
__launch_bounds__(256)
__global__ void head_reduce_kernel(const float* __restrict__ part, const float* __restrict__ bvec,
                                   OUT* __restrict__ hout) {
    int i = blockIdx.x * blockDim.x + threadIdx.x;   // NNODES*8 float4-units
    if (i >= NNODES * (NC / 4)) return;
    int d = i >> 3, c4 = (i & 7) * 4;
    f32x4 s = {0.f, 0.f, 0.f, 0.f};
    #pragma unroll
    for (int sl = 0; sl < NSLICE; sl++) {
        f32x4 v = *(const f32x4*)&part[((size_t)sl * NNODES + d) * NC + c4];
        s += v;
    }
    const f32x4 bv = *(const f32x4*)&bvec[c4];
    #pragma unroll
    for (int j = 0; j < 4; j++) {
        float r = s[j] * (1.0f / (float)NH) + bv[j];
        r = (r > 0.f) ? r : 0.01f * r;
        hout[(size_t)d * NC + c4 + j] = (OUT)r;
    }
}

// ---------------- fused pool + classifier (unchanged) ----------------
__launch_bounds__(1024)
__global__ void pool_classify_kernel(const float* __restrict__ h, const int* __restrict__ batch,
                                     const float* __restrict__ Wc, const float* __restrict__ bc,
                                     float* __restrict__ out) {
    int g = blockIdx.x;
    int lo = 0, hi = NNODES;
    while (lo < hi) { int mid = (lo + hi) >> 1; if (batch[mid] < g) lo = mid + 1; else hi = mid; }
    int start = lo;
    hi = NNODES;
    while (lo < hi) { int mid = (lo + hi) >> 1; if (batch[mid] <= g) lo = mid + 1; else hi = mid; }
    int endn = lo;
    int cntg = endn - start;

    int tid = threadIdx.x;
    int c = tid & 31, nl = tid >> 5;              // 32 node-lanes x 32 channels
    float s = 0.f;
    for (int n = start + nl; n < endn; n += 32) s += h[n * NC + c];
    __shared__ float red[1024];
    red[tid] = s;
    __syncthreads();
    if (tid < 32) {
        float t = 0.f;
        #pragma unroll
        for (int j = 0; j < 32; j++) t += red[j * 32 + tid];
        red[tid] = t / fmaxf((float)cntg, 1.0f);
    }
    __syncthreads();
    if (tid < NCLASSES) {
        float sum = bc[tid];
        #pragma unroll
        for (int cc = 0; cc < NC; cc++) sum += red[cc] * Wc[cc * NCLASSES + tid];
        out[g * NCLASSES + tid] = sum;
    }
}

// ---------------- launch ----------------

extern "C" void kernel_launch(void* const* d_in, const int* in_sizes, int n_in,
                              void* d_out, int out_size, void* d_ws, size_t ws_size,
                              hipStream_t stream) {
    const float* x    = (const float*)d_in[0];
    const float* Wl1  = (const float*)d_in[1];
    const float* bl1  = (const float*)d_in[2];
    const float* Wr1  = (const float*)d_in[3];
    const float* br1  = (const float*)d_in[4];
    const float* att1 = (const float*)d_in[5];
    const float* b1   = (const float*)d_in[6];
    const float* Wl2  = (const float*)d_in[7];
    const float* bl2  = (const float*)d_in[8];
    const float* Wr2  = (const float*)d_in[9];
    const float* br2  = (const float*)d_in[10];
    const float* att2 = (const float*)d_in[11];
    const float* b2   = (const float*)d_in[12];
    const float* Wc   = (const float*)d_in[13];
    const float* bc   = (const float*)d_in[14];
    const int* ei     = (const int*)d_in[15];
    const int* batch  = (const int*)d_in[16];
    float* out = (float*)d_out;

    const int* srcp = ei;
    const int* dstp = ei + NEDGES;

    char* ws = (char*)d_ws;
    size_t off = 0;
    auto alloc = [&](size_t bytes) -> void* {
        void* p = ws + off;
        off += (bytes + 255) & ~(size_t)255;
        return p;
    };
    _Float16* xlh  = (_Float16*)alloc(sizeof(_Float16) * (size_t)NNODES * HC);
    _Float16* xrh  = (_Float16*)alloc(sizeof(_Float16) * (size_t)NNODES * HC);
    _Float16* xh   = (_Float16*)alloc(sizeof(_Float16) * (size_t)NNODES * NFEATK);
    _Float16* h1   = (_Float16*)alloc(sizeof(_Float16) * (size_t)NNODES * NC);
    float* h2      = (float*)alloc(sizeof(float) * (size_t)NNODES * NC);
    float* part    = (float*)alloc(sizeof(float) * (size_t)NSLICE * NNODES * NC);
    _Float16* Wlt1 = (_Float16*)alloc(sizeof(_Float16) * 512 * NFEATK);
    _Float16* Wrt1 = (_Float16*)alloc(sizeof(_Float16) * 512 * NFEATK);
    _Float16* Wlt2 = (_Float16*)alloc(sizeof(_Float16) * 512 * NC);
    _Float16* Wrt2 = (_Float16*)alloc(sizeof(_Float16) * 512 * NC);
    int*   cnt     = (int*)alloc(sizeof(int) * NNODES);
    unsigned short* csr = (unsigned short*)alloc(sizeof(unsigned short) * (size_t)NNODES * CAP);

    // prep: conversions + bucket init (one dispatch)
    prep0_kernel<<<512, 256, 0, stream>>>(x, xh, Wl1, Wr1, Wlt1, Wrt1,
                                          Wl2, Wr2, Wlt2, Wrt2, cnt, csr);
    // bucket scatter (one atomic pass; no count/scan)
    scatter_kernel<<<(NEDGES + 255) / 256, 256, 0, stream>>>(srcp, dstp, cnt, csr);

    const int MB = (NNODES + 63) / 64;     // 469
    const int EB = (NNODES / 8) * NSLICE;  // 30000 edge-stage blocks
    const int RB = (NNODES * (NC / 4) + 255) / 256;

    // Layer 1
    dual_gemm_kernel<NFEATK><<<dim3(MB, 8), 256, 0, stream>>>(xh, Wlt1, Wrt1, bl1, br1, xlh, xrh);
    gat_edge_kernel<<<EB, 256, 0, stream>>>(xlh, xrh, att1, cnt, csr, part);
    head_reduce_kernel<_Float16><<<RB, 256, 0, stream>>>(part, b1, h1);

    // Layer 2
    dual_gemm_kernel<NC><<<dim3(MB, 8), 256, 0, stream>>>(h1, Wlt2, Wrt2, bl2, br2, xlh, xrh);
    gat_edge_kernel<<<EB, 256, 0, stream>>>(xlh, xrh, att2, cnt, csr, part);
    head_reduce_kernel<float><<<RB, 256, 0, stream>>>(part, b2, h2);

    // Pool + classify
    pool_classify_kernel<<<NG, 1024, 0, stream>>>(h2, batch, Wc, bc, out);
}

// Round 5
// 347.247 us; speedup vs baseline: 1.3888x; 1.0584x over previous
//
#include <hip/hip_runtime.h>
#include <float.h>

#define NNODES 30000
#define NEDGES 480000
#define NFEATK 128
#define NH 16
#define NC 32
#define HC 512            // NH*NC
#define NCLASSES 10
#define NG 64
#define CAP 96            // padded per-node edge capacity (max deg ~45 for Poisson(16))
#define NR 16             // src-sort ranges: 2048 nodes = 2MB of xlh per range

using half2v = __attribute__((ext_vector_type(2))) _Float16;
using half4 = __attribute__((ext_vector_type(4))) _Float16;
using half8 = __attribute__((ext_vector_type(8))) _Float16;
using f32x4 = __attribute__((ext_vector_type(4))) float;

// ---------------- merged prep: conversions + cnt16 zero ----------------
__global__ void prep0_kernel(const float* __restrict__ x, _Float16* __restrict__ xh,
                             const float* __restrict__ Wl1, const float* __restrict__ Wr1,
                             _Float16* __restrict__ Wlt1, _Float16* __restrict__ Wrt1,
                             const float* __restrict__ Wl2, const float* __restrict__ Wr2,
                             _Float16* __restrict__ Wlt2, _Float16* __restrict__ Wrt2,
                             int* __restrict__ cnt16) {
    int gtid = blockIdx.x * blockDim.x + threadIdx.x;
    int gstride = gridDim.x * blockDim.x;
    // x -> fp16 (float4-granular)
    for (int i = gtid; i < NNODES * NFEATK / 4; i += gstride) {
        float4 v = *(const float4*)&x[i * 4];
        half4 h = {(_Float16)v.x, (_Float16)v.y, (_Float16)v.z, (_Float16)v.w};
        *(half4*)&xh[i * 4] = h;
    }
    // W1 transposes (both l and r)
    for (int i = gtid; i < 2 * 512 * NFEATK; i += gstride) {
        int sel = i >= 512 * NFEATK;
        int idx = i - sel * 512 * NFEATK;
        const float* W = sel ? Wr1 : Wl1;
        _Float16* Wt = sel ? Wrt1 : Wlt1;
        int n = idx & 511, k = idx >> 9;
        Wt[n * NFEATK + k] = (_Float16)W[idx];
    }
    // W2 transposes
    for (int i = gtid; i < 2 * 512 * NC; i += gstride) {
        int sel = i >= 512 * NC;
        int idx = i - sel * 512 * NC;
        const float* W = sel ? Wr2 : Wl2;
        _Float16* Wt = sel ? Wrt2 : Wlt2;
        int n = idx & 511, k = idx >> 9;
        Wt[n * NC + k] = (_Float16)W[idx];
    }
    // zero per-(node,range) counters
    for (int i = gtid; i < NNODES * NR; i += gstride) cnt16[i] = 0;
}

// ---------------- pass 1: count edges per (dst, src-range) ----------------
// items [0,NEDGES) = real edges; [NEDGES, NEDGES+NNODES) = self loops.
__global__ void count_kernel(const int* __restrict__ src, const int* __restrict__ dst,
                             int* __restrict__ cnt16) {
    int i = blockIdx.x * blockDim.x + threadIdx.x;
    if (i >= NEDGES + NNODES) return;
    int s, d;
    if (i < NEDGES) { s = src[i]; d = dst[i]; }
    else            { d = i - NEDGES; s = d; }
    atomicAdd(&cnt16[d * NR + (s >> 11)], 1);
}

// ---------------- pass 2: per-node exclusive scan -> absolute cursors ----------------
__global__ void scan_kernel(const int* __restrict__ cnt16, int* __restrict__ cur16,
                            int* __restrict__ cnt) {
    int d = blockIdx.x * blockDim.x + threadIdx.x;
    if (d >= NNODES) return;
    int run = 0;
    #pragma unroll
    for (int r = 0; r < NR; r++) {
        int c = cnt16[d * NR + r];
        cur16[d * NR + r] = d * CAP + run;   // absolute csr index
        run += c;
    }
    cnt[d] = run;                            // total degree incl. self loop
}

// ---------------- pass 3: bucketed scatter (src-sorted adjacency) ----------------
__global__ void scatter_kernel(const int* __restrict__ src, const int* __restrict__ dst,
                               int* __restrict__ cur16, unsigned short* __restrict__ csr) {
    int i = blockIdx.x * blockDim.x + threadIdx.x;
    if (i >= NEDGES + NNODES) return;
    int s, d;
    if (i < NEDGES) { s = src[i]; d = dst[i]; }
    else            { d = i - NEDGES; s = d; }
    int pos = atomicAdd(&cur16[d * NR + (s >> 11)], 1);
    csr[pos] = (unsigned short)s;
}

// ---------------- dual MFMA GEMM (grid transposed for A-tile L2 reuse) ----------------
template <int K>
__launch_bounds__(256)
__global__ void dual_gemm_kernel(const _Float16* __restrict__ A,
                                 const _Float16* __restrict__ Wlt, const _Float16* __restrict__ Wrt,
                                 const float* __restrict__ bl, const float* __restrict__ br,
                                 _Float16* __restrict__ Yl, _Float16* __restrict__ Yr) {
    constexpr int Kc = K / 8;
    constexpr int AH = 64 * K;
    constexpr int BH = 128 * K;
    constexpr int YSH = 64 * 136;
    constexpr int SMEMH = (AH + BH > YSH) ? (AH + BH) : YSH;
    __shared__ __align__(16) _Float16 smem[SMEMH];
    _Float16* as = smem;
    _Float16* bs = smem + AH;

    int tid = threadIdx.x;
    // blockIdx.x in [0,8): the 8 (sel,nbase) variants sharing one A-tile are
    // dispatch-adjacent -> A-tile stays in L2 across its 8 uses.
    int sel = blockIdx.x >> 2;
    int nbase = (blockIdx.x & 3) * 128;
    const _Float16* Bt = sel ? Wrt : Wlt;
    const float* bias = sel ? br : bl;
    _Float16* Y = sel ? Yr : Yl;
    int mb = blockIdx.y;

    for (int c = tid; c < 64 * Kc; c += 256) {
        int row = c / Kc, k8 = c % Kc;
        int arow = mb * 64 + row; if (arow > NNODES - 1) arow = NNODES - 1;
        half8 v = *(const half8*)&A[(size_t)arow * K + k8 * 8];
        *(half8*)&as[(row * Kc + (k8 ^ (row & (Kc - 1)))) * 8] = v;
    }
    for (int c = tid; c < 128 * Kc; c += 256) {
        int row = c / Kc, k8 = c % Kc;
        half8 v = *(const half8*)&Bt[(size_t)(nbase + row) * K + k8 * 8];
        *(half8*)&bs[(row * Kc + (k8 ^ (row & (Kc - 1)))) * 8] = v;
    }
    __syncthreads();

    int wave = tid >> 6, lane = tid & 63;
    int quad = lane >> 4, l16 = lane & 15;
    int am = l16 & (Kc - 1);

    f32x4 acc[8];
    #pragma unroll
    for (int f = 0; f < 8; f++) acc[f] = (f32x4){0.f, 0.f, 0.f, 0.f};

    #pragma unroll
    for (int kk = 0; kk < Kc; kk += 4) {
        int k8 = (kk + quad) ^ am;
        half8 a = *(const half8*)&as[((wave * 16 + l16) * Kc + k8) * 8];
        #pragma unroll
        for (int f = 0; f < 8; f++) {
            half8 b = *(const half8*)&bs[((f * 16 + l16) * Kc + k8) * 8];
            acc[f] = __builtin_amdgcn_mfma_f32_16x16x32_f16(a, b, acc[f], 0, 0, 0);
        }
    }
    __syncthreads();

    _Float16* ys = smem;
    #pragma unroll
    for (int f = 0; f < 8; f++) {
        float bv = bias[nbase + f * 16 + l16];
        #pragma unroll
        for (int r = 0; r < 4; r++) {
            ys[(wave * 16 + quad * 4 + r) * 136 + f * 16 + l16] = (_Float16)(acc[f][r] + bv);
        }
    }
    __syncthreads();
    int mtop = mb * 64;
    for (int c = tid; c < 64 * 16; c += 256) {
        int r = c >> 4, cc = (c & 15) * 8;
        int grow = mtop + r;
        if (grow < NNODES)
            *(half8*)&Y[(size_t)grow * HC + nbase + cc] = *(half8*)&ys[r * 136 + cc];
    }
}

// ---------------- fused GATv2 edge stage: 4 nodes/block, 1 wave/node (R2 structure) ----------------
// Adjacency lists are src-sorted: co-resident waves sweep src space in near-lockstep,
// so the instantaneous gather working set is a sliding window << 30MB -> L2 hits.
__device__ inline half2v lrelu2(half2v e) {
    half2v s = e * half2v{(_Float16)0.2f, (_Float16)0.2f};
    return __builtin_elementwise_max(e, s);
}

#if __has_builtin(__builtin_amdgcn_fdot2)
#define FDOT2(a, b, c) __builtin_amdgcn_fdot2((a), (b), (c), false)
#else
__device__ inline float fdot2_sw(half2v a, half2v b, float c) {
    half2v p = a * b;
    return c + (float)p.x + (float)p.y;
}
#define FDOT2(a, b, c) fdot2_sw((a), (b), (c))
#endif

template <typename OUT>
__launch_bounds__(256)
__global__ void gat_edge_kernel(const _Float16* __restrict__ xlh, const _Float16* __restrict__ xrh,
                                const float* __restrict__ att, const float* __restrict__ bvec,
                                const int* __restrict__ cnt, const unsigned short* __restrict__ csr_src,
                                OUT* __restrict__ hout) {
    int wv = threadIdx.x >> 6;           // wave in block -> node slot
    int t = threadIdx.x & 63;            // lane in wave
    int d = blockIdx.x * 4 + wv;         // dst node (NNODES % 4 == 0)
    int col = t * 8;                     // head = t/4, 4 lanes per head

    half8 xrq = *(const half8*)&xrh[(unsigned)d * HC + col];
    half2v xr0 = {xrq[0], xrq[1]}, xr1 = {xrq[2], xrq[3]};
    half2v xr2 = {xrq[4], xrq[5]}, xr3 = {xrq[6], xrq[7]};
    float4 atta = *(const float4*)&att[col];
    float4 attb = *(const float4*)&att[col + 4];
    half2v at0 = {(_Float16)atta.x, (_Float16)atta.y};
    half2v at1 = {(_Float16)atta.z, (_Float16)atta.w};
    half2v at2 = {(_Float16)attb.x, (_Float16)attb.y};
    half2v at3 = {(_Float16)attb.z, (_Float16)attb.w};

    int beg = d * CAP, end = beg + cnt[d];

    float l = 0.f;
    float a[8];
    #pragma unroll
    for (int c = 0; c < 8; c++) a[c] = 0.f;

    for (int i = beg; i < end; i += 4) {
        int n = end - i;
        int s0 = csr_src[i];
        int s1 = csr_src[n > 1 ? i + 1 : i];
        int s2 = csr_src[n > 2 ? i + 2 : i];
        int s3 = csr_src[n > 3 ? i + 3 : i];
        half8 q0 = *(const half8*)&xlh[(unsigned)s0 * HC + col];
        half8 q1 = *(const half8*)&xlh[(unsigned)s1 * HC + col];
        half8 q2 = *(const half8*)&xlh[(unsigned)s2 * HC + col];
        half8 q3 = *(const half8*)&xlh[(unsigned)s3 * HC + col];

        // packed-f16 score: e = leaky(xl+xr); v += dot2(e, att)  (f32 accumulate)
        float v0 = 0.f, v1 = 0.f, v2 = 0.f, v3 = 0.f;
        v0 = FDOT2(lrelu2(half2v{q0[0], q0[1]} + xr0), at0, v0);
        v0 = FDOT2(lrelu2(half2v{q0[2], q0[3]} + xr1), at1, v0);
        v0 = FDOT2(lrelu2(half2v{q0[4], q0[5]} + xr2), at2, v0);
        v0 = FDOT2(lrelu2(half2v{q0[6], q0[7]} + xr3), at3, v0);
        v1 = FDOT2(lrelu2(half2v{q1[0], q1[1]} + xr0), at0, v1);
        v1 = FDOT2(lrelu2(half2v{q1[2], q1[3]} + xr1), at1, v1);
        v1 = FDOT2(lrelu2(half2v{q1[4], q1[5]} + xr2), at2, v1);
        v1 = FDOT2(lrelu2(half2v{q1[6], q1[7]} + xr3), at3, v1);
        v2 = FDOT2(lrelu2(half2v{q2[0], q2[1]} + xr0), at0, v2);
        v2 = FDOT2(lrelu2(half2v{q2[2], q2[3]} + xr1), at1, v2);
        v2 = FDOT2(lrelu2(half2v{q2[4], q2[5]} + xr2), at2, v2);
        v2 = FDOT2(lrelu2(half2v{q2[6], q2[7]} + xr3), at3, v2);
        v3 = FDOT2(lrelu2(half2v{q3[0], q3[1]} + xr0), at0, v3);
        v3 = FDOT2(lrelu2(half2v{q3[2], q3[3]} + xr1), at1, v3);
        v3 = FDOT2(lrelu2(half2v{q3[4], q3[5]} + xr2), at2, v3);
        v3 = FDOT2(lrelu2(half2v{q3[6], q3[7]} + xr3), at3, v3);

        // head reduce: 4 lanes per head -> 2 butterfly levels
        v0 += __shfl_xor(v0, 1); v1 += __shfl_xor(v1, 1);
        v2 += __shfl_xor(v2, 1); v3 += __shfl_xor(v3, 1);
        v0 += __shfl_xor(v0, 2); v1 += __shfl_xor(v1, 2);
        v2 += __shfl_xor(v2, 2); v3 += __shfl_xor(v3, 2);

        float p0 = __expf(v0);
        float p1 = (n > 1) ? __expf(v1) : 0.f;
        float p2 = (n > 2) ? __expf(v2) : 0.f;
        float p3 = (n > 3) ? __expf(v3) : 0.f;
        l += (p0 + p1) + (p2 + p3);

        // aggregation: f32 accumulate, f16 operand -> v_fma_mix
        #pragma unroll
        for (int c = 0; c < 8; c++) {
            a[c] += p0 * (float)q0[c];
            a[c] += p1 * (float)q1[c];
            a[c] += p2 * (float)q2[c];
            a[c] += p3 * (float)q3[c];
        }
    }

    // normalize per (node, head) BEFORE head-mean: l is uniform within a
    // 4-lane head group, distinct across heads.
    float inv = 1.0f / l;
    #pragma unroll
    for (int c = 0; c < 8; c++) a[c] *= inv;

    // head-mean in-register: sum over the 16 lanes with equal (t & 3)
    #pragma unroll
    for (int off = 4; off < 64; off <<= 1) {
        #pragma unroll
        for (int c = 0; c < 8; c++) a[c] += __shfl_xor(a[c], off);
    }

    if (t < 4) {
        #pragma unroll
        for (int c = 0; c < 8; c++) {
            float r = a[c] * (1.0f / (float)NH) + bvec[t * 8 + c];
            r = (r > 0.f) ? r : 0.01f * r;
            hout[(size_t)d * NC + t * 8 + c] = (OUT)r;
        }
    }
}

// ---------------- fused pool + classifier (unchanged) ----------------
__launch_bounds__(1024)
__global__ void pool_classify_kernel(const float* __restrict__ h, const int* __restrict__ batch,
                                     const float* __restrict__ Wc, const float* __restrict__ bc,
                                     float* __restrict__ out) {
    int g = blockIdx.x;
    int lo = 0, hi = NNODES;
    while (lo < hi) { int mid = (lo + hi) >> 1; if (batch[mid] < g) lo = mid + 1; else hi = mid; }
    int start = lo;
    hi = NNODES;
    while (lo < hi) { int mid = (lo + hi) >> 1; if (batch[mid] <= g) lo = mid + 1; else hi = mid; }
    int endn = lo;
    int cntg = endn - start;

    int tid = threadIdx.x;
    int c = tid & 31, nl = tid >> 5;              // 32 node-lanes x 32 channels
    float s = 0.f;
    for (int n = start + nl; n < endn; n += 32) s += h[n * NC + c];
    __shared__ float red[1024];
    red[tid] = s;
    __syncthreads();
    if (tid < 32) {
        float t = 0.f;
        #pragma unroll
        for (int j = 0; j < 32; j++) t += red[j * 32 + tid];
        red[tid] = t / fmaxf((float)cntg, 1.0f);
    }
    __syncthreads();
    if (tid < NCLASSES) {
        float sum = bc[tid];
        #pragma unroll
        for (int cc = 0; cc < NC; cc++) sum += red[cc] * Wc[cc * NCLASSES + tid];
        out[g * NCLASSES + tid] = sum;
    }
}

// ---------------- launch ----------------

extern "C" void kernel_launch(void* const* d_in, const int* in_sizes, int n_in,
                              void* d_out, int out_size, void* d_ws, size_t ws_size,
                              hipStream_t stream) {
    const float* x    = (const float*)d_in[0];
    const float* Wl1  = (const float*)d_in[1];
    const float* bl1  = (const float*)d_in[2];
    const float* Wr1  = (const float*)d_in[3];
    const float* br1  = (const float*)d_in[4];
    const float* att1 = (const float*)d_in[5];
    const float* b1   = (const float*)d_in[6];
    const float* Wl2  = (const float*)d_in[7];
    const float* bl2  = (const float*)d_in[8];
    const float* Wr2  = (const float*)d_in[9];
    const float* br2  = (const float*)d_in[10];
    const float* att2 = (const float*)d_in[11];
    const float* b2   = (const float*)d_in[12];
    const float* Wc   = (const float*)d_in[13];
    const float* bc   = (const float*)d_in[14];
    const int* ei     = (const int*)d_in[15];
    const int* batch  = (const int*)d_in[16];
    float* out = (float*)d_out;

    const int* srcp = ei;
    const int* dstp = ei + NEDGES;

    char* ws = (char*)d_ws;
    size_t off = 0;
    auto alloc = [&](size_t bytes) -> void* {
        void* p = ws + off;
        off += (bytes + 255) & ~(size_t)255;
        return p;
    };
    _Float16* xlh  = (_Float16*)alloc(sizeof(_Float16) * (size_t)NNODES * HC);
    _Float16* xrh  = (_Float16*)alloc(sizeof(_Float16) * (size_t)NNODES * HC);
    _Float16* xh   = (_Float16*)alloc(sizeof(_Float16) * (size_t)NNODES * NFEATK);
    _Float16* h1   = (_Float16*)alloc(sizeof(_Float16) * (size_t)NNODES * NC);
    float* h2      = (float*)alloc(sizeof(float) * (size_t)NNODES * NC);
    _Float16* Wlt1 = (_Float16*)alloc(sizeof(_Float16) * 512 * NFEATK);
    _Float16* Wrt1 = (_Float16*)alloc(sizeof(_Float16) * 512 * NFEATK);
    _Float16* Wlt2 = (_Float16*)alloc(sizeof(_Float16) * 512 * NC);
    _Float16* Wrt2 = (_Float16*)alloc(sizeof(_Float16) * 512 * NC);
    int*   cnt     = (int*)alloc(sizeof(int) * NNODES);
    int*   cnt16   = (int*)alloc(sizeof(int) * (size_t)NNODES * NR);
    int*   cur16   = (int*)alloc(sizeof(int) * (size_t)NNODES * NR);
    unsigned short* csr = (unsigned short*)alloc(sizeof(unsigned short) * (size_t)NNODES * CAP);

    const int EI = (NEDGES + NNODES + 255) / 256;   // edges + self-loops

    // prep: conversions + counter zero
    prep0_kernel<<<512, 256, 0, stream>>>(x, xh, Wl1, Wr1, Wlt1, Wrt1,
                                          Wl2, Wr2, Wlt2, Wrt2, cnt16);
    // src-sorted CSR build: count -> scan -> scatter
    count_kernel<<<EI, 256, 0, stream>>>(srcp, dstp, cnt16);
    scan_kernel<<<(NNODES + 255) / 256, 256, 0, stream>>>(cnt16, cur16, cnt);
    scatter_kernel<<<EI, 256, 0, stream>>>(srcp, dstp, cur16, csr);

    const int MB = (NNODES + 63) / 64;   // 469

    // Layer 1
    dual_gemm_kernel<NFEATK><<<dim3(8, MB), 256, 0, stream>>>(xh, Wlt1, Wrt1, bl1, br1, xlh, xrh);
    gat_edge_kernel<_Float16><<<NNODES / 4, 256, 0, stream>>>(xlh, xrh, att1, b1, cnt, csr, h1);

    // Layer 2
    dual_gemm_kernel<NC><<<dim3(8, MB), 256, 0, stream>>>(h1, Wlt2, Wrt2, bl2, br2, xlh, xrh);
    gat_edge_kernel<float><<<NNODES / 4, 256, 0, stream>>>(xlh, xrh, att2, b2, cnt, csr, h2);

    // Pool + classify
    pool_classify_kernel<<<NG, 1024, 0, stream>>>(h2, batch, Wc, bc, out);
}

// Round 6
// 319.843 us; speedup vs baseline: 1.5078x; 1.0857x over previous
//
#include <hip/hip_runtime.h>
#include <float.h>

#define NNODES 30000
#define NEDGES 480000
#define NFEATK 128
#define NH 16
#define NC 32
#define HC 512            // NH*NC
#define NCLASSES 10
#define NG 64
#define CAP 96            // padded per-node edge capacity (max deg ~45 for Poisson(16))

using half2v = __attribute__((ext_vector_type(2))) _Float16;
using half4 = __attribute__((ext_vector_type(4))) _Float16;
using half8 = __attribute__((ext_vector_type(8))) _Float16;
using f32x4 = __attribute__((ext_vector_type(4))) float;

// ---------------- merged prep: conversions + bucket init ----------------
__global__ void prep0_kernel(const float* __restrict__ x, _Float16* __restrict__ xh,
                             const float* __restrict__ Wl1, const float* __restrict__ Wr1,
                             _Float16* __restrict__ Wlt1, _Float16* __restrict__ Wrt1,
                             const float* __restrict__ Wl2, const float* __restrict__ Wr2,
                             _Float16* __restrict__ Wlt2, _Float16* __restrict__ Wrt2,
                             int* __restrict__ cnt, unsigned short* __restrict__ csr) {
    int gtid = blockIdx.x * blockDim.x + threadIdx.x;
    int gstride = gridDim.x * blockDim.x;
    // x -> fp16 (float4-granular)
    for (int i = gtid; i < NNODES * NFEATK / 4; i += gstride) {
        float4 v = *(const float4*)&x[i * 4];
        half4 h = {(_Float16)v.x, (_Float16)v.y, (_Float16)v.z, (_Float16)v.w};
        *(half4*)&xh[i * 4] = h;
    }
    // W1 transposes (both l and r)
    for (int i = gtid; i < 2 * 512 * NFEATK; i += gstride) {
        int sel = i >= 512 * NFEATK;
        int idx = i - sel * 512 * NFEATK;
        const float* W = sel ? Wr1 : Wl1;
        _Float16* Wt = sel ? Wrt1 : Wlt1;
        int n = idx & 511, k = idx >> 9;
        Wt[n * NFEATK + k] = (_Float16)W[idx];
    }
    // W2 transposes
    for (int i = gtid; i < 2 * 512 * NC; i += gstride) {
        int sel = i >= 512 * NC;
        int idx = i - sel * 512 * NC;
        const float* W = sel ? Wr2 : Wl2;
        _Float16* Wt = sel ? Wrt2 : Wlt2;
        int n = idx & 511, k = idx >> 9;
        Wt[n * NC + k] = (_Float16)W[idx];
    }
    // bucket init: self-loop in slot 0, cnt = 1
    for (int i = gtid; i < NNODES; i += gstride) {
        cnt[i] = 1;
        csr[i * CAP] = (unsigned short)i;
    }
}

// ---------------- bucket scatter: one atomic pass, u16 payload ----------------
__global__ void scatter_kernel(const int* __restrict__ src, const int* __restrict__ dst,
                               int* __restrict__ cnt, unsigned short* __restrict__ csr) {
    int e = blockIdx.x * blockDim.x + threadIdx.x;
    if (e >= NEDGES) return;
    int s = src[e], d = dst[e];
    int pos = atomicAdd(&cnt[d], 1);
    csr[d * CAP + pos] = (unsigned short)s;
}

// ---------------- dual MFMA GEMM: K-split staging for 2x occupancy ----------------
// LDS per block: K=128 -> 24 KB (was 48 KB) => 6 blocks/CU instead of 3.
template <int K>
__launch_bounds__(256)
__global__ void dual_gemm_kernel(const _Float16* __restrict__ A,
                                 const _Float16* __restrict__ Wlt, const _Float16* __restrict__ Wrt,
                                 const float* __restrict__ bl, const float* __restrict__ br,
                                 _Float16* __restrict__ Yl, _Float16* __restrict__ Yr) {
    constexpr int KS = (K > 64) ? 64 : K;    // staged K-chunk
    constexpr int KcS = KS / 8;              // half8 units per chunk row
    constexpr int AH = 64 * KS;
    constexpr int BH = 128 * KS;
    constexpr int YSH = 64 * 136;
    constexpr int SMEMH = (AH + BH > YSH) ? (AH + BH) : YSH;
    __shared__ __align__(16) _Float16 smem[SMEMH];
    _Float16* as = smem;
    _Float16* bs = smem + AH;

    int tid = threadIdx.x;
    // blockIdx.x in [0,8): the 8 (sel,nbase) variants sharing one A-tile are
    // dispatch-adjacent -> A-tile stays in L2 across its 8 uses.
    int sel = blockIdx.x >> 2;
    int nbase = (blockIdx.x & 3) * 128;
    const _Float16* Bt = sel ? Wrt : Wlt;
    const float* bias = sel ? br : bl;
    _Float16* Y = sel ? Yr : Yl;
    int mb = blockIdx.y;

    int wave = tid >> 6, lane = tid & 63;
    int quad = lane >> 4, l16 = lane & 15;
    int am = l16 & (KcS - 1);

    f32x4 acc[8];
    #pragma unroll
    for (int f = 0; f < 8; f++) acc[f] = (f32x4){0.f, 0.f, 0.f, 0.f};

    #pragma unroll
    for (int ko = 0; ko < K / KS; ++ko) {
        if (ko) __syncthreads();             // protect LDS reuse across chunks
        for (int c = tid; c < 64 * KcS; c += 256) {
            int row = c / KcS, k8 = c % KcS;
            int arow = mb * 64 + row; if (arow > NNODES - 1) arow = NNODES - 1;
            half8 v = *(const half8*)&A[(size_t)arow * K + (ko * KcS + k8) * 8];
            *(half8*)&as[(row * KcS + (k8 ^ (row & (KcS - 1)))) * 8] = v;
        }
        for (int c = tid; c < 128 * KcS; c += 256) {
            int row = c / KcS, k8 = c % KcS;
            half8 v = *(const half8*)&Bt[(size_t)(nbase + row) * K + (ko * KcS + k8) * 8];
            *(half8*)&bs[(row * KcS + (k8 ^ (row & (KcS - 1)))) * 8] = v;
        }
        __syncthreads();

        #pragma unroll
        for (int kk = 0; kk < KcS; kk += 4) {
            int k8 = (kk + quad) ^ am;
            half8 a = *(const half8*)&as[((wave * 16 + l16) * KcS + k8) * 8];
            #pragma unroll
            for (int f = 0; f < 8; f++) {
                half8 b = *(const half8*)&bs[((f * 16 + l16) * KcS + k8) * 8];
                acc[f] = __builtin_amdgcn_mfma_f32_16x16x32_f16(a, b, acc[f], 0, 0, 0);
            }
        }
    }
    __syncthreads();

    _Float16* ys = smem;
    #pragma unroll
    for (int f = 0; f < 8; f++) {
        float bv = bias[nbase + f * 16 + l16];
        #pragma unroll
        for (int r = 0; r < 4; r++) {
            ys[(wave * 16 + quad * 4 + r) * 136 + f * 16 + l16] = (_Float16)(acc[f][r] + bv);
        }
    }
    __syncthreads();
    int mtop = mb * 64;
    for (int c = tid; c < 64 * 16; c += 256) {
        int r = c >> 4, cc = (c & 15) * 8;
        int grow = mtop + r;
        if (grow < NNODES)
            *(half8*)&Y[(size_t)grow * HC + nbase + cc] = *(half8*)&ys[r * 136 + cc];
    }
}

// ---------------- fused GATv2 edge stage: 4 nodes/block, 1 wave/node ----------------
__device__ inline half2v lrelu2(half2v e) {
    // leaky(e) = max(e, 0.2*e) since slope 0.2 in (0,1)
    half2v s = e * half2v{(_Float16)0.2f, (_Float16)0.2f};
    return __builtin_elementwise_max(e, s);
}

#if __has_builtin(__builtin_amdgcn_fdot2)
#define FDOT2(a, b, c) __builtin_amdgcn_fdot2((a), (b), (c), false)
#else
__device__ inline float fdot2_sw(half2v a, half2v b, float c) {
    half2v p = a * b;
    return c + (float)p.x + (float)p.y;
}
#define FDOT2(a, b, c) fdot2_sw((a), (b), (c))
#endif

template <typename OUT>
__launch_bounds__(256)
__global__ void gat_edge_kernel(const _Float16* __restrict__ xlh, const _Float16* __restrict__ xrh,
                                const float* __restrict__ att, const float* __restrict__ bvec,
                                const int* __restrict__ cnt, const unsigned short* __restrict__ csr_src,
                                OUT* __restrict__ hout) {
    int wv = threadIdx.x >> 6;           // wave in block -> node slot
    int t = threadIdx.x & 63;            // lane in wave
    int d = blockIdx.x * 4 + wv;         // dst node (NNODES % 4 == 0)
    int col = t * 8;                     // head = t/4, 4 lanes per head

    half8 xrq = *(const half8*)&xrh[(unsigned)d * HC + col];
    half2v xr0 = {xrq[0], xrq[1]}, xr1 = {xrq[2], xrq[3]};
    half2v xr2 = {xrq[4], xrq[5]}, xr3 = {xrq[6], xrq[7]};
    float4 atta = *(const float4*)&att[col];
    float4 attb = *(const float4*)&att[col + 4];
    half2v at0 = {(_Float16)atta.x, (_Float16)atta.y};
    half2v at1 = {(_Float16)atta.z, (_Float16)atta.w};
    half2v at2 = {(_Float16)attb.x, (_Float16)attb.y};
    half2v at3 = {(_Float16)attb.z, (_Float16)attb.w};

    int beg = d * CAP, end = beg + cnt[d];

    float l = 0.f;
    float a[8];
    #pragma unroll
    for (int c = 0; c < 8; c++) a[c] = 0.f;

    for (int i = beg; i < end; i += 4) {
        int n = end - i;
        int s0 = csr_src[i];
        int s1 = csr_src[n > 1 ? i + 1 : i];
        int s2 = csr_src[n > 2 ? i + 2 : i];
        int s3 = csr_src[n > 3 ? i + 3 : i];
        half8 q0 = *(const half8*)&xlh[(unsigned)s0 * HC + col];
        half8 q1 = *(const half8*)&xlh[(unsigned)s1 * HC + col];
        half8 q2 = *(const half8*)&xlh[(unsigned)s2 * HC + col];
        half8 q3 = *(const half8*)&xlh[(unsigned)s3 * HC + col];

        // packed-f16 score: e = leaky(xl+xr); v += dot2(e, att)  (f32 accumulate)
        float v0 = 0.f, v1 = 0.f, v2 = 0.f, v3 = 0.f;
        v0 = FDOT2(lrelu2(half2v{q0[0], q0[1]} + xr0), at0, v0);
        v0 = FDOT2(lrelu2(half2v{q0[2], q0[3]} + xr1), at1, v0);
        v0 = FDOT2(lrelu2(half2v{q0[4], q0[5]} + xr2), at2, v0);
        v0 = FDOT2(lrelu2(half2v{q0[6], q0[7]} + xr3), at3, v0);
        v1 = FDOT2(lrelu2(half2v{q1[0], q1[1]} + xr0), at0, v1);
        v1 = FDOT2(lrelu2(half2v{q1[2], q1[3]} + xr1), at1, v1);
        v1 = FDOT2(lrelu2(half2v{q1[4], q1[5]} + xr2), at2, v1);
        v1 = FDOT2(lrelu2(half2v{q1[6], q1[7]} + xr3), at3, v1);
        v2 = FDOT2(lrelu2(half2v{q2[0], q2[1]} + xr0), at0, v2);
        v2 = FDOT2(lrelu2(half2v{q2[2], q2[3]} + xr1), at1, v2);
        v2 = FDOT2(lrelu2(half2v{q2[4], q2[5]} + xr2), at2, v2);
        v2 = FDOT2(lrelu2(half2v{q2[6], q2[7]} + xr3), at3, v2);
        v3 = FDOT2(lrelu2(half2v{q3[0], q3[1]} + xr0), at0, v3);
        v3 = FDOT2(lrelu2(half2v{q3[2], q3[3]} + xr1), at1, v3);
        v3 = FDOT2(lrelu2(half2v{q3[4], q3[5]} + xr2), at2, v3);
        v3 = FDOT2(lrelu2(half2v{q3[6], q3[7]} + xr3), at3, v3);

        // head reduce: 4 lanes per head -> 2 butterfly levels
        v0 += __shfl_xor(v0, 1); v1 += __shfl_xor(v1, 1);
        v2 += __shfl_xor(v2, 1); v3 += __shfl_xor(v3, 1);
        v0 += __shfl_xor(v0, 2); v1 += __shfl_xor(v1, 2);
        v2 += __shfl_xor(v2, 2); v3 += __shfl_xor(v3, 2);

        float p0 = __expf(v0);
        float p1 = (n > 1) ? __expf(v1) : 0.f;
        float p2 = (n > 2) ? __expf(v2) : 0.f;
        float p3 = (n > 3) ? __expf(v3) : 0.f;
        l += (p0 + p1) + (p2 + p3);

        // aggregation: f32 accumulate, f16 operand -> v_fma_mix
        #pragma unroll
        for (int c = 0; c < 8; c++) {
            a[c] += p0 * (float)q0[c];
            a[c] += p1 * (float)q1[c];
            a[c] += p2 * (float)q2[c];
            a[c] += p3 * (float)q3[c];
        }
    }

    // normalize per (node, head) BEFORE head-mean: l is uniform within a
    // 4-lane head group, distinct across heads.
    float inv = 1.0f / l;
    #pragma unroll
    for (int c = 0; c < 8; c++) a[c] *= inv;

    // head-mean in-register: sum over the 16 lanes with equal (t & 3)
    #pragma unroll
    for (int off = 4; off < 64; off <<= 1) {
        #pragma unroll
        for (int c = 0; c < 8; c++) a[c] += __shfl_xor(a[c], off);
    }

    if (t < 4) {
        #pragma unroll
        for (int c = 0; c < 8; c++) {
            float r = a[c] * (1.0f / (float)NH) + bvec[t * 8 + c];
            r = (r > 0.f) ? r : 0.01f * r;
            hout[(size_t)d * NC + t * 8 + c] = (OUT)r;
        }
    }
}

// ---------------- fused pool + classifier (unchanged) ----------------
__launch_bounds__(1024)
__global__ void pool_classify_kernel(const float* __restrict__ h, const int* __restrict__ batch,
                                     const float* __restrict__ Wc, const float* __restrict__ bc,
                                     float* __restrict__ out) {
    int g = blockIdx.x;
    int lo = 0, hi = NNODES;
    while (lo < hi) { int mid = (lo + hi) >> 1; if (batch[mid] < g) lo = mid + 1; else hi = mid; }
    int start = lo;
    hi = NNODES;
    while (lo < hi) { int mid = (lo + hi) >> 1; if (batch[mid] <= g) lo = mid + 1; else hi = mid; }
    int endn = lo;
    int cntg = endn - start;

    int tid = threadIdx.x;
    int c = tid & 31, nl = tid >> 5;              // 32 node-lanes x 32 channels
    float s = 0.f;
    for (int n = start + nl; n < endn; n += 32) s += h[n * NC + c];
    __shared__ float red[1024];
    red[tid] = s;
    __syncthreads();
    if (tid < 32) {
        float t = 0.f;
        #pragma unroll
        for (int j = 0; j < 32; j++) t += red[j * 32 + tid];
        red[tid] = t / fmaxf((float)cntg, 1.0f);
    }
    __syncthreads();
    if (tid < NCLASSES) {
        float sum = bc[tid];
        #pragma unroll
        for (int cc = 0; cc < NC; cc++) sum += red[cc] * Wc[cc * NCLASSES + tid];
        out[g * NCLASSES + tid] = sum;
    }
}

// ---------------- launch ----------------

extern "C" void kernel_launch(void* const* d_in, const int* in_sizes, int n_in,
                              void* d_out, int out_size, void* d_ws, size_t ws_size,
                              hipStream_t stream) {
    const float* x    = (const float*)d_in[0];
    const float* Wl1  = (const float*)d_in[1];
    const float* bl1  = (const float*)d_in[2];
    const float* Wr1  = (const float*)d_in[3];
    const float* br1  = (const float*)d_in[4];
    const float* att1 = (const float*)d_in[5];
    const float* b1   = (const float*)d_in[6];
    const float* Wl2  = (const float*)d_in[7];
    const float* bl2  = (const float*)d_in[8];
    const float* Wr2  = (const float*)d_in[9];
    const float* br2  = (const float*)d_in[10];
    const float* att2 = (const float*)d_in[11];
    const float* b2   = (const float*)d_in[12];
    const float* Wc   = (const float*)d_in[13];
    const float* bc   = (const float*)d_in[14];
    const int* ei     = (const int*)d_in[15];
    const int* batch  = (const int*)d_in[16];
    float* out = (float*)d_out;

    const int* srcp = ei;
    const int* dstp = ei + NEDGES;

    char* ws = (char*)d_ws;
    size_t off = 0;
    auto alloc = [&](size_t bytes) -> void* {
        void* p = ws + off;
        off += (bytes + 255) & ~(size_t)255;
        return p;
    };
    _Float16* xlh  = (_Float16*)alloc(sizeof(_Float16) * (size_t)NNODES * HC);
    _Float16* xrh  = (_Float16*)alloc(sizeof(_Float16) * (size_t)NNODES * HC);
    _Float16* xh   = (_Float16*)alloc(sizeof(_Float16) * (size_t)NNODES * NFEATK);
    _Float16* h1   = (_Float16*)alloc(sizeof(_Float16) * (size_t)NNODES * NC);
    float* h2      = (float*)alloc(sizeof(float) * (size_t)NNODES * NC);
    _Float16* Wlt1 = (_Float16*)alloc(sizeof(_Float16) * 512 * NFEATK);
    _Float16* Wrt1 = (_Float16*)alloc(sizeof(_Float16) * 512 * NFEATK);
    _Float16* Wlt2 = (_Float16*)alloc(sizeof(_Float16) * 512 * NC);
    _Float16* Wrt2 = (_Float16*)alloc(sizeof(_Float16) * 512 * NC);
    int*   cnt     = (int*)alloc(sizeof(int) * NNODES);
    unsigned short* csr = (unsigned short*)alloc(sizeof(unsigned short) * (size_t)NNODES * CAP);

    // prep: conversions + bucket init (one dispatch)
    prep0_kernel<<<512, 256, 0, stream>>>(x, xh, Wl1, Wr1, Wlt1, Wrt1,
                                          Wl2, Wr2, Wlt2, Wrt2, cnt, csr);
    // bucket scatter (one atomic pass; no count/scan)
    scatter_kernel<<<(NEDGES + 255) / 256, 256, 0, stream>>>(srcp, dstp, cnt, csr);

    const int MB = (NNODES + 63) / 64;   // 469

    // Layer 1
    dual_gemm_kernel<NFEATK><<<dim3(8, MB), 256, 0, stream>>>(xh, Wlt1, Wrt1, bl1, br1, xlh, xrh);
    gat_edge_kernel<_Float16><<<NNODES / 4, 256, 0, stream>>>(xlh, xrh, att1, b1, cnt, csr, h1);

    // Layer 2
    dual_gemm_kernel<NC><<<dim3(8, MB), 256, 0, stream>>>(h1, Wlt2, Wrt2, bl2, br2, xlh, xrh);
    gat_edge_kernel<float><<<NNODES / 4, 256, 0, stream>>>(xlh, xrh, att2, b2, cnt, csr, h2);

    // Pool + classify
    pool_classify_kernel<<<NG, 1024, 0, stream>>>(h2, batch, Wc, bc, out);
}